// Round 17
// baseline (114.582 us; speedup 1.0000x reference)
//
#include <hip/hip_runtime.h>
#include <math.h>

#define LEV_N  155    // n_levels for bits=8,k=2,signed
#define NPOS   78     // nonneg levels: 0 + 77 positive
#define NBUCK  4096   // uniform buckets over y in [0,1); width 2^-12 == min level gap
#define BW     (1.0f / 4096.0f)
#define BLK    512    // 4 blocks/CU x 34KB LDS = 136KB, 32 waves/CU

typedef float vfloat4 __attribute__((ext_vector_type(4)));

// Bit-exact vs reference (proven R9-R16, absmax 0.0):
//   xc = clamp(x,-a,a); xn = xc * fl(1/a); y = |xn|; neg = xn<0
//   b = floor(y*4096) (exact, pow2); pr = sLUT[b] (== sPair[j(b)], proven R11)
//   d0=|y-pr.x|, d1=|pr.y-y|; up = neg ? d0>=d1 : d0>d1; q = sign-applied pick
//   out = q*a + (x-xc)   (pass-through STE tail beyond clip)
__device__ __forceinline__ float quant_one(
    float xe, float a, float r,
    const float2* __restrict__ sLUT)
{
#pragma clang fp contract(off)
    const float xc = fminf(fmaxf(xe, -a), a);
    const float xn = __fmul_rn(xc, r);          // reciprocal-multiply (== ref)
    const float y  = fabsf(xn);
    const bool  neg = (xn < 0.0f);
    const float u = __fmul_rn(y, 4096.0f);      // exact (power-of-two scale)
    int b = (int)u;                              // trunc == floor (y >= 0)
    b = min(b, NBUCK - 1);
    const float2 pr = sLUT[b];                   // ONE independent LDS b64
    const float d0 = fabsf(__fsub_rn(y, pr.x));  // == ref |xn-l0| bits
    const float d1 = fabsf(__fsub_rn(pr.y, y));  // == ref |xn-l1| bits
    const bool up = neg ? (d0 >= d1) : (d0 > d1);
    const float qm = up ? pr.y : pr.x;
    const float q  = neg ? -qm : qm;
    return __fadd_rn(__fmul_rn(q, a), __fsub_rn(xe, xc));
}

__device__ __forceinline__ vfloat4 quant_vec(
    vfloat4 xv, float a, float r,
    const float2* __restrict__ sLUT)
{
    vfloat4 ov;
    ov.x = quant_one(xv.x, a, r, sLUT);
    ov.y = quant_one(xv.y, a, r, sLUT);
    ov.z = quant_one(xv.z, a, r, sLUT);
    ov.w = quant_one(xv.w, a, r, sLUT);
    return ov;
}

__global__ __launch_bounds__(BLK) void apot_quant_lut(
    const float* __restrict__ x,
    const float* __restrict__ alpha_p,
    const float* __restrict__ levels,
    float* __restrict__ out,
    long long n_elem, float g)
{
#pragma clang fp contract(off)
    __shared__ float  sP[NPOS];
    __shared__ float  sM[NPOS];          // midpoints m[0..76] + huge pad at [77]
    __shared__ float2 sPair[NPOS + 1];   // clamped consecutive pairs, idx 0..78
    __shared__ float2 sLUT[NBUCK];       // bucket -> (l0,l1) pair, 32 KB

    const int t = threadIdx.x;
    if (t < NPOS) sP[t] = levels[(LEV_N - NPOS) + t];
    __syncthreads();
    if (t < NPOS - 1)
        sM[t] = __fmul_rn(__fadd_rn(sP[t], sP[t + 1]), 0.5f);  // exact in f32
    if (t == NPOS - 1) sM[t] = 3.0e38f;
    if (t <= NPOS) {
        int j0 = max(t - 1, 0);
        int j1 = min(t, NPOS - 1);
        sPair[t] = make_float2(sP[j0], sP[j1]);
    }
    __syncthreads();

    // Build sLUT: monotone walk, NBUCK/BLK = 8 buckets per thread.
    // j(b) = 1 + #(midpoints < b*BW); sLUT[b] = sPair[j(b)] (== R11 semantics).
    {
        const int b0 = t * (NBUCK / BLK);
        const float s0 = (float)b0 * BW;             // exact
        int lo = 0, hi = NPOS - 1;                   // count over m[0..76]
        #pragma unroll
        for (int it = 0; it < 7; ++it) {             // cnt = #(m < s0)
            int mid = (lo + hi) >> 1;
            bool c = sM[mid] < s0;
            lo = c ? mid + 1 : lo;
            hi = c ? hi : mid;
        }
        int cnt = lo;
        for (int k = 0; k < NBUCK / BLK; ++k) {
            float s = (float)(b0 + k) * BW;          // exact
            while (cnt < NPOS - 1 && sM[cnt] < s) ++cnt;
            sLUT[b0 + k] = sPair[cnt + 1];
        }
    }
    __syncthreads();

    // a = max((alpha - alpha*g) + alpha*g, EPS), f32 ops, no contraction
    const float alpha = alpha_p[0];
    const float ag = __fmul_rn(alpha, g);
    const float a  = fmaxf(__fadd_rn(__fsub_rn(alpha, ag), ag), 1e-8f);
    const float r  = 1.0f / a;

    const long long nvec = n_elem >> 2;
    const long long gid = (long long)blockIdx.x * blockDim.x + t;
    const long long stride = (long long)gridDim.x * blockDim.x;
    const vfloat4* __restrict__ xv4 = reinterpret_cast<const vfloat4*>(x);
    vfloat4* __restrict__ ov4 = reinterpret_cast<vfloat4*>(out);

    // A/B vs R16: loads now PLAIN too (R16 isolated the store flag: nt store
    // cost ~10us; this isolates the load flag). Everything else identical.
    long long idx = gid;
    for (; idx + stride < nvec; idx += 2 * stride) {
        vfloat4 v0 = xv4[idx];
        vfloat4 v1 = xv4[idx + stride];
        vfloat4 o0 = quant_vec(v0, a, r, sLUT);
        vfloat4 o1 = quant_vec(v1, a, r, sLUT);
        ov4[idx] = o0;
        ov4[idx + stride] = o1;
    }
    for (; idx < nvec; idx += stride) {
        vfloat4 v0 = xv4[idx];
        vfloat4 o0 = quant_vec(v0, a, r, sLUT);
        ov4[idx] = o0;
    }
    for (long long i = (nvec << 2) + gid; i < n_elem; i += stride)
        out[i] = quant_one(x[i], a, r, sLUT);
}

// ---- fallback: proven R9 kernel (absmax 0.0), used if n_levels != 155 ----
#define LEV_MAX 256
__global__ __launch_bounds__(256) void apot_quant_kernel(
    const float* __restrict__ x,
    const float* __restrict__ alpha_p,
    const float* __restrict__ levels,
    float* __restrict__ out,
    int n_levels, long long n_elem, float g)
{
#pragma clang fp contract(off)
    __shared__ float s_lev[LEV_MAX];
    const int t = threadIdx.x;
    for (int i = t; i < LEV_MAX; i += blockDim.x)
        s_lev[i] = (i < n_levels) ? levels[i] : 3.0e38f;
    __syncthreads();
    const float alpha = alpha_p[0];
    const float ag = __fmul_rn(alpha, g);
    const float a  = fmaxf(__fadd_rn(__fsub_rn(alpha, ag), ag), 1e-8f);
    const float r = 1.0f / a;
    const int nm1 = n_levels - 1;
    const long long gid = (long long)blockIdx.x * blockDim.x + t;
    const long long stride = (long long)gridDim.x * blockDim.x;
    for (long long i = gid; i < n_elem; i += stride) {
        const float xe = x[i];
        const float xc = fminf(fmaxf(xe, -a), a);
        const float xn = __fmul_rn(xc, r);
        int lo = 0, hi = n_levels;
        for (int it = 0; it < 8; ++it) {
            int mid = (lo + hi) >> 1;
            bool cc = s_lev[mid] < xn;
            lo = cc ? mid + 1 : lo;
            hi = cc ? hi : mid;
        }
        int p0 = min(max(lo - 1, 0), nm1);
        int p1 = min(lo, nm1);
        float l0 = s_lev[p0];
        float l1 = s_lev[p1];
        float q = (fabsf(__fsub_rn(xn, l0)) > fabsf(__fsub_rn(xn, l1))) ? l1 : l0;
        out[i] = __fadd_rn(__fmul_rn(q, a), __fsub_rn(xe, xc));
    }
}

extern "C" void kernel_launch(void* const* d_in, const int* in_sizes, int n_in,
                              void* d_out, int out_size, void* d_ws, size_t ws_size,
                              hipStream_t stream) {
    const float* x      = (const float*)d_in[0];
    const float* alpha  = (const float*)d_in[1];
    const float* levels = (const float*)d_in[2];
    float* out = (float*)d_out;

    const long long n_elem = (long long)in_sizes[0];
    const int n_levels = in_sizes[2];
    const float g = (float)(1.0 / sqrt((double)n_elem));

    if (n_levels == LEV_N) {
        long long nvec = n_elem >> 2;
        long long want = (nvec + BLK - 1) / BLK;
        int grid = (int)(want < 1024 ? (want > 0 ? want : 1) : 1024);
        apot_quant_lut<<<grid, BLK, 0, stream>>>(x, alpha, levels, out,
                                                 n_elem, g);
    } else {
        const int block = 256;
        long long want = (n_elem + block - 1) / block;
        int grid = (int)(want < 2048 ? (want > 0 ? want : 1) : 2048);
        apot_quant_kernel<<<grid, block, 0, stream>>>(x, alpha, levels, out,
                                                      n_levels, n_elem, g);
    }
}

// Round 18
// 93.327 us; speedup vs baseline: 1.2278x; 1.2278x over previous
//
#include <hip/hip_runtime.h>
#include <math.h>

#define LEV_N  155    // n_levels for bits=8,k=2,signed
#define NPOS   78     // nonneg levels: 0 + 77 positive
#define NBUCK  4096   // uniform buckets over y in [0,1); width 2^-12 == min level gap
#define BW     (1.0f / 4096.0f)
#define BLK    512    // 4 blocks/CU x 34KB LDS = 136KB, 32 waves/CU

// native clang vector type: accepted by __builtin_nontemporal_load/store
typedef float vfloat4 __attribute__((ext_vector_type(4)));

// Bit-exact vs reference (proven R9-R17, absmax 0.0):
//   xc = clamp(x,-a,a); xn = xc * fl(1/a); y = |xn|; neg = xn<0
//   b = floor(y*4096) (exact, pow2); pr = sLUT[b] (== sPair[j(b)], proven R11)
//   d0=|y-pr.x|, d1=|pr.y-y|; up = neg ? d0>=d1 : d0>d1; q = sign-applied pick
//   out = q*a + (x-xc)   (pass-through STE tail beyond clip)
//
// Memory-path config (isolated R14/R16/R17): NT loads (+20us win) +
// PLAIN stores (nt stores cost 10us) — gfx950 L2 retains the write
// stream, drops the read-once stream.
__device__ __forceinline__ float quant_one(
    float xe, float a, float r,
    const float2* __restrict__ sLUT)
{
#pragma clang fp contract(off)
    const float xc = fminf(fmaxf(xe, -a), a);
    const float xn = __fmul_rn(xc, r);          // reciprocal-multiply (== ref)
    const float y  = fabsf(xn);
    const bool  neg = (xn < 0.0f);
    const float u = __fmul_rn(y, 4096.0f);      // exact (power-of-two scale)
    int b = (int)u;                              // trunc == floor (y >= 0)
    b = min(b, NBUCK - 1);
    const float2 pr = sLUT[b];                   // ONE independent LDS b64
    const float d0 = fabsf(__fsub_rn(y, pr.x));  // == ref |xn-l0| bits
    const float d1 = fabsf(__fsub_rn(pr.y, y));  // == ref |xn-l1| bits
    const bool up = neg ? (d0 >= d1) : (d0 > d1);
    const float qm = up ? pr.y : pr.x;
    const float q  = neg ? -qm : qm;
    return __fadd_rn(__fmul_rn(q, a), __fsub_rn(xe, xc));
}

__device__ __forceinline__ vfloat4 quant_vec(
    vfloat4 xv, float a, float r,
    const float2* __restrict__ sLUT)
{
    vfloat4 ov;
    ov.x = quant_one(xv.x, a, r, sLUT);
    ov.y = quant_one(xv.y, a, r, sLUT);
    ov.z = quant_one(xv.z, a, r, sLUT);
    ov.w = quant_one(xv.w, a, r, sLUT);
    return ov;
}

__global__ __launch_bounds__(BLK) void apot_quant_lut(
    const float* __restrict__ x,
    const float* __restrict__ alpha_p,
    const float* __restrict__ levels,
    float* __restrict__ out,
    long long n_elem, float g)
{
#pragma clang fp contract(off)
    __shared__ float  sP[NPOS];
    __shared__ float  sM[NPOS];          // midpoints m[0..76] + huge pad at [77]
    __shared__ float2 sPair[NPOS + 1];   // clamped consecutive pairs, idx 0..78
    __shared__ float2 sLUT[NBUCK];       // bucket -> (l0,l1) pair, 32 KB

    const int t = threadIdx.x;
    if (t < NPOS) sP[t] = levels[(LEV_N - NPOS) + t];
    __syncthreads();
    if (t < NPOS - 1)
        sM[t] = __fmul_rn(__fadd_rn(sP[t], sP[t + 1]), 0.5f);  // exact in f32
    if (t == NPOS - 1) sM[t] = 3.0e38f;
    if (t <= NPOS) {
        int j0 = max(t - 1, 0);
        int j1 = min(t, NPOS - 1);
        sPair[t] = make_float2(sP[j0], sP[j1]);
    }
    __syncthreads();

    // Build sLUT: monotone walk, NBUCK/BLK = 8 buckets per thread.
    // j(b) = 1 + #(midpoints < b*BW); sLUT[b] = sPair[j(b)] (== R11 semantics).
    {
        const int b0 = t * (NBUCK / BLK);
        const float s0 = (float)b0 * BW;             // exact
        int lo = 0, hi = NPOS - 1;                   // count over m[0..76]
        #pragma unroll
        for (int it = 0; it < 7; ++it) {             // cnt = #(m < s0)
            int mid = (lo + hi) >> 1;
            bool c = sM[mid] < s0;
            lo = c ? mid + 1 : lo;
            hi = c ? hi : mid;
        }
        int cnt = lo;
        for (int k = 0; k < NBUCK / BLK; ++k) {
            float s = (float)(b0 + k) * BW;          // exact
            while (cnt < NPOS - 1 && sM[cnt] < s) ++cnt;
            sLUT[b0 + k] = sPair[cnt + 1];
        }
    }
    __syncthreads();

    // a = max((alpha - alpha*g) + alpha*g, EPS), f32 ops, no contraction
    const float alpha = alpha_p[0];
    const float ag = __fmul_rn(alpha, g);
    const float a  = fmaxf(__fadd_rn(__fsub_rn(alpha, ag), ag), 1e-8f);
    const float r  = 1.0f / a;

    const long long nvec = n_elem >> 2;
    const long long gid = (long long)blockIdx.x * blockDim.x + t;
    const long long stride = (long long)gridDim.x * blockDim.x;
    const vfloat4* __restrict__ xv4 = reinterpret_cast<const vfloat4*>(x);
    vfloat4* __restrict__ ov4 = reinterpret_cast<vfloat4*>(out);

    // R16 config: NT loads, plain stores, 2x unrolled grid-stride.
    long long idx = gid;
    for (; idx + stride < nvec; idx += 2 * stride) {
        vfloat4 v0 = __builtin_nontemporal_load(&xv4[idx]);
        vfloat4 v1 = __builtin_nontemporal_load(&xv4[idx + stride]);
        vfloat4 o0 = quant_vec(v0, a, r, sLUT);
        vfloat4 o1 = quant_vec(v1, a, r, sLUT);
        ov4[idx] = o0;
        ov4[idx + stride] = o1;
    }
    for (; idx < nvec; idx += stride) {
        vfloat4 v0 = __builtin_nontemporal_load(&xv4[idx]);
        vfloat4 o0 = quant_vec(v0, a, r, sLUT);
        ov4[idx] = o0;
    }
    for (long long i = (nvec << 2) + gid; i < n_elem; i += stride)
        out[i] = quant_one(x[i], a, r, sLUT);
}

// ---- fallback: proven R9 kernel (absmax 0.0), used if n_levels != 155 ----
#define LEV_MAX 256
__global__ __launch_bounds__(256) void apot_quant_kernel(
    const float* __restrict__ x,
    const float* __restrict__ alpha_p,
    const float* __restrict__ levels,
    float* __restrict__ out,
    int n_levels, long long n_elem, float g)
{
#pragma clang fp contract(off)
    __shared__ float s_lev[LEV_MAX];
    const int t = threadIdx.x;
    for (int i = t; i < LEV_MAX; i += blockDim.x)
        s_lev[i] = (i < n_levels) ? levels[i] : 3.0e38f;
    __syncthreads();
    const float alpha = alpha_p[0];
    const float ag = __fmul_rn(alpha, g);
    const float a  = fmaxf(__fadd_rn(__fsub_rn(alpha, ag), ag), 1e-8f);
    const float r = 1.0f / a;
    const int nm1 = n_levels - 1;
    const long long gid = (long long)blockIdx.x * blockDim.x + t;
    const long long stride = (long long)gridDim.x * blockDim.x;
    for (long long i = gid; i < n_elem; i += stride) {
        const float xe = x[i];
        const float xc = fminf(fmaxf(xe, -a), a);
        const float xn = __fmul_rn(xc, r);
        int lo = 0, hi = n_levels;
        for (int it = 0; it < 8; ++it) {
            int mid = (lo + hi) >> 1;
            bool cc = s_lev[mid] < xn;
            lo = cc ? mid + 1 : lo;
            hi = cc ? hi : mid;
        }
        int p0 = min(max(lo - 1, 0), nm1);
        int p1 = min(lo, nm1);
        float l0 = s_lev[p0];
        float l1 = s_lev[p1];
        float q = (fabsf(__fsub_rn(xn, l0)) > fabsf(__fsub_rn(xn, l1))) ? l1 : l0;
        out[i] = __fadd_rn(__fmul_rn(q, a), __fsub_rn(xe, xc));
    }
}

extern "C" void kernel_launch(void* const* d_in, const int* in_sizes, int n_in,
                              void* d_out, int out_size, void* d_ws, size_t ws_size,
                              hipStream_t stream) {
    const float* x      = (const float*)d_in[0];
    const float* alpha  = (const float*)d_in[1];
    const float* levels = (const float*)d_in[2];
    float* out = (float*)d_out;

    const long long n_elem = (long long)in_sizes[0];
    const int n_levels = in_sizes[2];
    const float g = (float)(1.0 / sqrt((double)n_elem));

    if (n_levels == LEV_N) {
        long long nvec = n_elem >> 2;
        long long want = (nvec + BLK - 1) / BLK;
        int grid = (int)(want < 1024 ? (want > 0 ? want : 1) : 1024);
        apot_quant_lut<<<grid, BLK, 0, stream>>>(x, alpha, levels, out,
                                                 n_elem, g);
    } else {
        const int block = 256;
        long long want = (n_elem + block - 1) / block;
        int grid = (int)(want < 2048 ? (want > 0 ? want : 1) : 2048);
        apot_quant_kernel<<<grid, block, 0, stream>>>(x, alpha, levels, out,
                                                      n_levels, n_elem, g);
    }
}